// Round 1
// baseline (452.412 us; speedup 1.0000x reference)
//
#include <hip/hip_runtime.h>

// N=524288 rows, K=128, outd=256 cols, num_grid=255
#define M_TOTAL     524288
#define KDIM        128
#define NCOL        256
#define NITER       (M_TOTAL / 32)     // 16384 iterations of 32 rows (2 subtiles of 16)
#define GRID_BLOCKS 2048               // -> 8 iterations per block
#define LOG2E       1.44269504088896340736f

typedef _Float16 half8   __attribute__((ext_vector_type(8)));
typedef float    floatx4 __attribute__((ext_vector_type(4)));

// DPP prefix-sum within each 16-lane group (VALU pipe, no DS traffic).
// After shr 1,2,4,8 lane (15 mod 16) holds the 16-lane total.
template <int CTRL>
__device__ __forceinline__ float dpp_add_step(float x) {
    int xi = __builtin_bit_cast(int, x);
    int sh = __builtin_amdgcn_update_dpp(0, xi, CTRL, 0xF, 0xF, true);
    return x + __builtin_bit_cast(float, sh);
}
__device__ __forceinline__ float row16_sum(float x) {
    x = dpp_add_step<0x111>(x);  // row_shr:1
    x = dpp_add_step<0x112>(x);  // row_shr:2
    x = dpp_add_step<0x114>(x);  // row_shr:4
    x = dpp_add_step<0x118>(x);  // row_shr:8
    return x;
}

// waves_per_eu(2,4): min=2 keeps the allocator at a 256-VGPR budget (R2 evidence:
// default heuristic went to 84 VGPR -> remat/spill, WRITE_SIZE 9.5MB). max raised
// 2->4: R3 counters showed Occupancy pinned at 21.6% (=2 waves/EU) with both pipes
// idle (MfmaUtil 14%, VALUBusy 36%, HBM 8.7%) -> latency-bound; let the HW run a
// 3rd/4th wave per SIMD if the unified RF allows.
__global__ __attribute__((amdgpu_flat_work_group_size(256, 256), amdgpu_waves_per_eu(2, 4)))
void density_kernel(const float* __restrict__ t,
                    const float* __restrict__ x,
                    const float* __restrict__ w,     // [128][256] row-major
                    const float* __restrict__ bias,  // [256]
                    float* __restrict__ out)
{
    // per-wave partials: [parity][subtile][row-in-16][wave] = (denom, numer)
    __shared__ alignas(16) float2 part[2][2][16][4];

    const int tid  = threadIdx.x;
    const int wave = tid >> 6;        // 0..3, owns cols [wave*64, wave*64+64)
    const int lane = tid & 63;
    const int n    = lane & 15;       // col-in-16 (B/C) == row-in-16 (A)
    const int q    = lane >> 4;       // quad selector
    const int colbase = wave * 64;

    // ---- B fragments resident in VGPRs for the whole kernel.
    // fp16(W * log2e): exp(logit) == exp2(logit') with logits' = A@(W*log2e) + b*log2e.
    // B layout for mfma_f32_16x16x32_f16: lane supplies B[k = q*8+j][n]
    half8 bfrag[4][4];   // [coltile][kstep]
    float biasv[4], colf[4];
    #pragma unroll
    for (int ct = 0; ct < 4; ++ct) {
        const int col = colbase + ct * 16 + n;
        #pragma unroll
        for (int ks = 0; ks < 4; ++ks) {
            const int k0 = ks * 32 + q * 8;
            half8 b;
            #pragma unroll
            for (int j = 0; j < 8; ++j)
                b[j] = (_Float16)(w[(k0 + j) * NCOL + col] * LOG2E);
            bfrag[ct][ks] = b;
        }
        biasv[ct] = bias[col] * LOG2E;
        colf[ct]  = (float)col;
    }

    int p = 0;
    for (int it = blockIdx.x; it < NITER; it += GRID_BLOCKS) {
        const int row0 = it * 32;

        // ---- issue all global loads for both subtiles up front
        const float* arowA = x + (size_t)(row0 + n) * KDIM;
        const float* arowB = arowA + 16 * KDIM;
        floatx4 avA[4][2], avB[4][2];
        #pragma unroll
        for (int ks = 0; ks < 4; ++ks) {
            const floatx4* pA = (const floatx4*)(arowA + ks * 32 + q * 8);
            avA[ks][0] = pA[0];
            avA[ks][1] = pA[1];
        }
        #pragma unroll
        for (int ks = 0; ks < 4; ++ks) {
            const floatx4* pB = (const floatx4*)(arowB + ks * 32 + q * 8);
            avB[ks][0] = pB[0];
            avB[ks][1] = pB[1];
        }
        const floatx4 tvA = *(const floatx4*)(t + row0 + q * 4);
        const floatx4 tvB = *(const floatx4*)(t + row0 + 16 + q * 4);

        // ---- subtile A: fp16 2-pass split, MFMA
        floatx4 accA[4], accB[4];
        #pragma unroll
        for (int ct = 0; ct < 4; ++ct) {
            accA[ct] = (floatx4){biasv[ct], biasv[ct], biasv[ct], biasv[ct]};
            accB[ct] = accA[ct];
        }
        {
            half8 ahi[4], alo[4];
            #pragma unroll
            for (int ks = 0; ks < 4; ++ks) {
                const float* af = (const float*)&avA[ks][0];
                #pragma unroll
                for (int j = 0; j < 8; ++j) {
                    float a = af[j];
                    _Float16 h = (_Float16)a;
                    ahi[ks][j] = h;
                    alo[ks][j] = (_Float16)(a - (float)h);
                }
            }
            #pragma unroll
            for (int ks = 0; ks < 4; ++ks) {
                #pragma unroll
                for (int ct = 0; ct < 4; ++ct) {
                    accA[ct] = __builtin_amdgcn_mfma_f32_16x16x32_f16(ahi[ks], bfrag[ct][ks], accA[ct], 0, 0, 0);
                    accA[ct] = __builtin_amdgcn_mfma_f32_16x16x32_f16(alo[ks], bfrag[ct][ks], accA[ct], 0, 0, 0);
                }
            }
        }
        // ---- subtile B
        {
            half8 ahi[4], alo[4];
            #pragma unroll
            for (int ks = 0; ks < 4; ++ks) {
                const float* af = (const float*)&avB[ks][0];
                #pragma unroll
                for (int j = 0; j < 8; ++j) {
                    float a = af[j];
                    _Float16 h = (_Float16)a;
                    ahi[ks][j] = h;
                    alo[ks][j] = (_Float16)(a - (float)h);
                }
            }
            #pragma unroll
            for (int ks = 0; ks < 4; ++ks) {
                #pragma unroll
                for (int ct = 0; ct < 4; ++ct) {
                    accB[ct] = __builtin_amdgcn_mfma_f32_16x16x32_f16(ahi[ks], bfrag[ct][ks], accB[ct], 0, 0, 0);
                    accB[ct] = __builtin_amdgcn_mfma_f32_16x16x32_f16(alo[ks], bfrag[ct][ks], accB[ct], 0, 0, 0);
                }
            }
        }

        // ---- fused epilogues (hat-function interp, no max-sub: |logit| << 126)
        // out[row] = sum_c 2^z_c * max(0, 1-|c - t*255|) / sum_c 2^z_c
        float sA[4] = {0,0,0,0}, nmA[4] = {0,0,0,0};
        float sB[4] = {0,0,0,0}, nmB[4] = {0,0,0,0};
        #pragma unroll
        for (int ct = 0; ct < 4; ++ct) {
            #pragma unroll
            for (int r = 0; r < 4; ++r) {
                float eA = __builtin_amdgcn_exp2f(accA[ct][r]);
                float eB = __builtin_amdgcn_exp2f(accB[ct][r]);
                sA[r] += eA;
                sB[r] += eB;
                float wA = fmaxf(0.0f, 1.0f - fabsf(colf[ct] - tvA[r] * 255.0f));
                float wB = fmaxf(0.0f, 1.0f - fabsf(colf[ct] - tvB[r] * 255.0f));
                nmA[r] = fmaf(eA, wA, nmA[r]);
                nmB[r] = fmaf(eB, wB, nmB[r]);
            }
        }

        // ---- 16-lane reductions on the VALU pipe
        #pragma unroll
        for (int r = 0; r < 4; ++r) {
            sA[r]  = row16_sum(sA[r]);
            nmA[r] = row16_sum(nmA[r]);
            sB[r]  = row16_sum(sB[r]);
            nmB[r] = row16_sum(nmB[r]);
        }

        if (n == 15) {
            #pragma unroll
            for (int r = 0; r < 4; ++r) {
                part[p][0][q * 4 + r][wave] = make_float2(sA[r], nmA[r]);
                part[p][1][q * 4 + r][wave] = make_float2(sB[r], nmB[r]);
            }
        }
        __syncthreads();

        // ---- combine 4 wave-partials per row, store 32 outputs
        if (tid < 32) {
            const int st = tid >> 4, r = tid & 15;
            const float4* pr = (const float4*)&part[p][st][r][0];
            float4 a = pr[0], b = pr[1];
            float s  = a.x + a.z + b.x + b.z;
            float nm = a.y + a.w + b.y + b.w;
            out[row0 + tid] = nm / s;
        }
        p ^= 1;  // double-buffer: next iteration's writes can't race this combine
    }
}

extern "C" void kernel_launch(void* const* d_in, const int* in_sizes, int n_in,
                              void* d_out, int out_size, void* d_ws, size_t ws_size,
                              hipStream_t stream) {
    const float* t    = (const float*)d_in[0];
    const float* x    = (const float*)d_in[1];
    const float* wgt  = (const float*)d_in[2];
    const float* bias = (const float*)d_in[3];
    float* out = (float*)d_out;

    density_kernel<<<GRID_BLOCKS, 256, 0, stream>>>(t, x, wgt, bias, out);
}

// Round 2
// 375.451 us; speedup vs baseline: 1.2050x; 1.2050x over previous
//
#include <hip/hip_runtime.h>

// N=524288 rows, K=128, outd=256 cols, num_grid=255
#define M_TOTAL     524288
#define KDIM        128
#define NCOL        256
#define NITER       (M_TOTAL / 32)     // 16384 iterations of 32 rows
#define GRID_BLOCKS 2048
#define IPB         (NITER / GRID_BLOCKS)   // 8 iterations per block, exact
#define LOG2E       1.44269504088896340736f

typedef _Float16 half8   __attribute__((ext_vector_type(8)));
typedef float    floatx4 __attribute__((ext_vector_type(4)));

// DPP prefix-sum within each 16-lane group (VALU pipe, no DS traffic).
template <int CTRL>
__device__ __forceinline__ float dpp_add_step(float x) {
    int xi = __builtin_bit_cast(int, x);
    int sh = __builtin_amdgcn_update_dpp(0, xi, CTRL, 0xF, 0xF, true);
    return x + __builtin_bit_cast(float, sh);
}
__device__ __forceinline__ float row16_sum(float x) {
    x = dpp_add_step<0x111>(x);  // row_shr:1
    x = dpp_add_step<0x112>(x);  // row_shr:2
    x = dpp_add_step<0x114>(x);  // row_shr:4
    x = dpp_add_step<0x118>(x);  // row_shr:8
    return x;
}

// fp32 -> (hi,lo) fp16 2-pass split for 16 consecutive floats.
__device__ __forceinline__ void cvt16(const floatx4 pf[4],
                                      half8& h0, half8& h1, half8& l0, half8& l1) {
    const float* f = (const float*)pf;
    #pragma unroll
    for (int j = 0; j < 8; ++j) {
        float a = f[j];
        _Float16 h = (_Float16)a;
        h0[j] = h;
        l0[j] = (_Float16)(a - (float)h);
    }
    #pragma unroll
    for (int j = 0; j < 8; ++j) {
        float a = f[8 + j];
        _Float16 h = (_Float16)a;
        h1[j] = h;
        l1[j] = (_Float16)(a - (float)h);
    }
}

// waves_per_eu(2,4): min=2 keeps the allocator at a 256-VGPR budget (R2 evidence:
// default heuristic remat/spilled at 84 VGPR). R4 change: cooperative LDS staging
// of the A-tile (was: each of 4 waves loaded+converted the identical tile) +
// cross-iteration register prefetch to hide HBM/L2 latency under compute.
__global__ __attribute__((amdgpu_flat_work_group_size(256, 256), amdgpu_waves_per_eu(2, 4)))
void density_kernel(const float* __restrict__ t,
                    const float* __restrict__ x,
                    const float* __restrict__ w,     // [128][256] row-major
                    const float* __restrict__ bias,  // [256]
                    float* __restrict__ out)
{
    // per-wave partials: [parity][subtile][row-in-16][wave] = (denom, numer)
    __shared__ alignas(16) float2 part[2][2][16][4];
    // double-buffered hi/lo fp16 A-tile, chunk-XOR-swizzled:
    // element A[row][k] lives at tHi[p][row][(k>>3 ^ (row&7))*8 + (k&7)]
    __shared__ alignas(16) _Float16 tHi[2][32][128];
    __shared__ alignas(16) _Float16 tLo[2][32][128];

    const int tid  = threadIdx.x;
    const int wave = tid >> 6;        // 0..3, owns cols [wave*64, wave*64+64)
    const int lane = tid & 63;
    const int n    = lane & 15;       // col-in-16 (B/C) == row-in-16 (A)
    const int q    = lane >> 4;       // quad selector
    const int colbase = wave * 64;

    // ---- B fragments resident in VGPRs for the whole kernel.
    // fp16(W * log2e): exp(logit) == exp2(logit') with logits' = A@(W*log2e) + b*log2e.
    half8 bfrag[4][4];   // [coltile][kstep]
    float biasv[4], colf[4];
    #pragma unroll
    for (int ct = 0; ct < 4; ++ct) {
        const int col = colbase + ct * 16 + n;
        #pragma unroll
        for (int ks = 0; ks < 4; ++ks) {
            const int k0 = ks * 32 + q * 8;
            half8 b;
            #pragma unroll
            for (int j = 0; j < 8; ++j)
                b[j] = (_Float16)(w[(k0 + j) * NCOL + col] * LOG2E);
            bfrag[ct][ks] = b;
        }
        biasv[ct] = bias[col] * LOG2E;
        colf[ct]  = (float)col;
    }

    // ---- staging geometry: thread covers row sr, k in [sm*16, sm*16+16)
    const int sr  = tid >> 3;          // 0..31
    const int sm  = tid & 7;           // 0..7
    const int c0s = ((2 * sm)     ^ (sr & 7)) * 8;   // swizzled chunk offsets (halves)
    const int c1s = ((2 * sm + 1) ^ (sr & 7)) * 8;

    // fragment-read swizzled chunk offsets: chunk(ks) = ks*4+q -> ^(row&7) = ^(n&7)
    int rdc[4];
    #pragma unroll
    for (int ks = 0; ks < 4; ++ks) rdc[ks] = (((ks * 4 + q) ^ (n & 7)) * 8);

    // ---- prologue: stage tile(it=blockIdx.x) + its t values
    floatx4 tvA, tvB;
    {
        const int it0 = blockIdx.x;
        const float* src = x + (size_t)it0 * (32 * KDIM) + tid * 16;
        floatx4 pf[4];
        pf[0] = ((const floatx4*)src)[0];
        pf[1] = ((const floatx4*)src)[1];
        pf[2] = ((const floatx4*)src)[2];
        pf[3] = ((const floatx4*)src)[3];
        tvA = *(const floatx4*)(t + it0 * 32 + q * 4);
        tvB = *(const floatx4*)(t + it0 * 32 + 16 + q * 4);
        half8 h0, h1, l0, l1;
        cvt16(pf, h0, h1, l0, l1);
        *(half8*)&tHi[0][sr][c0s] = h0;
        *(half8*)&tHi[0][sr][c1s] = h1;
        *(half8*)&tLo[0][sr][c0s] = l0;
        *(half8*)&tLo[0][sr][c1s] = l1;
    }
    __syncthreads();

    int p = 0;
    #pragma unroll 1
    for (int ii = 0; ii < IPB; ++ii) {
        const int it   = blockIdx.x + ii * GRID_BLOCKS;
        const int row0 = it * 32;
        const int itn  = (ii + 1 < IPB) ? it + GRID_BLOCKS : it;  // last iter: dummy reload

        // ---- issue next tile's global loads NOW; consumed after the epilogue
        floatx4 pf[4];
        {
            const float* src = x + (size_t)itn * (32 * KDIM) + tid * 16;
            pf[0] = ((const floatx4*)src)[0];
            pf[1] = ((const floatx4*)src)[1];
            pf[2] = ((const floatx4*)src)[2];
            pf[3] = ((const floatx4*)src)[3];
        }
        const floatx4 tvAn = *(const floatx4*)(t + itn * 32 + q * 4);
        const floatx4 tvBn = *(const floatx4*)(t + itn * 32 + 16 + q * 4);

        // ---- A fragments from LDS (conflict-free via XOR swizzle)
        const _Float16* hiA = &tHi[p][n][0];
        const _Float16* loA = &tLo[p][n][0];
        const _Float16* hiB = &tHi[p][16 + n][0];
        const _Float16* loB = &tLo[p][16 + n][0];
        half8 ahiA[4], aloA[4], ahiB[4], aloB[4];
        #pragma unroll
        for (int ks = 0; ks < 4; ++ks) {
            ahiA[ks] = *(const half8*)&hiA[rdc[ks]];
            aloA[ks] = *(const half8*)&loA[rdc[ks]];
            ahiB[ks] = *(const half8*)&hiB[rdc[ks]];
            aloB[ks] = *(const half8*)&loB[rdc[ks]];
        }

        // ---- MFMA, fp16 2-pass
        floatx4 accA[4], accB[4];
        #pragma unroll
        for (int ct = 0; ct < 4; ++ct) {
            accA[ct] = (floatx4){biasv[ct], biasv[ct], biasv[ct], biasv[ct]};
            accB[ct] = accA[ct];
        }
        #pragma unroll
        for (int ks = 0; ks < 4; ++ks) {
            #pragma unroll
            for (int ct = 0; ct < 4; ++ct) {
                accA[ct] = __builtin_amdgcn_mfma_f32_16x16x32_f16(ahiA[ks], bfrag[ct][ks], accA[ct], 0, 0, 0);
                accA[ct] = __builtin_amdgcn_mfma_f32_16x16x32_f16(aloA[ks], bfrag[ct][ks], accA[ct], 0, 0, 0);
            }
        }
        #pragma unroll
        for (int ks = 0; ks < 4; ++ks) {
            #pragma unroll
            for (int ct = 0; ct < 4; ++ct) {
                accB[ct] = __builtin_amdgcn_mfma_f32_16x16x32_f16(ahiB[ks], bfrag[ct][ks], accB[ct], 0, 0, 0);
                accB[ct] = __builtin_amdgcn_mfma_f32_16x16x32_f16(aloB[ks], bfrag[ct][ks], accB[ct], 0, 0, 0);
            }
        }

        // ---- fused epilogues (hat-function interp; |logit| small, no max-sub)
        float sA[4] = {0,0,0,0}, nmA[4] = {0,0,0,0};
        float sB[4] = {0,0,0,0}, nmB[4] = {0,0,0,0};
        #pragma unroll
        for (int ct = 0; ct < 4; ++ct) {
            #pragma unroll
            for (int r = 0; r < 4; ++r) {
                float eA = __builtin_amdgcn_exp2f(accA[ct][r]);
                float eB = __builtin_amdgcn_exp2f(accB[ct][r]);
                sA[r] += eA;
                sB[r] += eB;
                float wA = fmaxf(0.0f, 1.0f - fabsf(colf[ct] - tvA[r] * 255.0f));
                float wB = fmaxf(0.0f, 1.0f - fabsf(colf[ct] - tvB[r] * 255.0f));
                nmA[r] = fmaf(eA, wA, nmA[r]);
                nmB[r] = fmaf(eB, wB, nmB[r]);
            }
        }

        // ---- 16-lane reductions on the VALU pipe
        #pragma unroll
        for (int r = 0; r < 4; ++r) {
            sA[r]  = row16_sum(sA[r]);
            nmA[r] = row16_sum(nmA[r]);
            sB[r]  = row16_sum(sB[r]);
            nmB[r] = row16_sum(nmB[r]);
        }

        if (n == 15) {
            #pragma unroll
            for (int r = 0; r < 4; ++r) {
                part[p][0][q * 4 + r][wave] = make_float2(sA[r], nmA[r]);
                part[p][1][q * 4 + r][wave] = make_float2(sB[r], nmB[r]);
            }
        }

        // ---- convert + publish next tile (vmcnt wait lands here, latency hidden)
        {
            half8 h0, h1, l0, l1;
            cvt16(pf, h0, h1, l0, l1);
            const int pn = p ^ 1;
            *(half8*)&tHi[pn][sr][c0s] = h0;
            *(half8*)&tHi[pn][sr][c1s] = h1;
            *(half8*)&tLo[pn][sr][c0s] = l0;
            *(half8*)&tLo[pn][sr][c1s] = l1;
        }
        __syncthreads();

        // ---- combine 4 wave-partials per row, store 32 outputs
        if (tid < 32) {
            const int st = tid >> 4, r = tid & 15;
            const float4* pr = (const float4*)&part[p][st][r][0];
            float4 a = pr[0], b = pr[1];
            float s  = a.x + a.z + b.x + b.z;
            float nm = a.y + a.w + b.y + b.w;
            out[row0 + tid] = nm / s;
        }
        tvA = tvAn;
        tvB = tvBn;
        p ^= 1;  // flips both the tile and part parities
    }
}

extern "C" void kernel_launch(void* const* d_in, const int* in_sizes, int n_in,
                              void* d_out, int out_size, void* d_ws, size_t ws_size,
                              hipStream_t stream) {
    const float* t    = (const float*)d_in[0];
    const float* x    = (const float*)d_in[1];
    const float* wgt  = (const float*)d_in[2];
    const float* bias = (const float*)d_in[3];
    float* out = (float*)d_out;

    density_kernel<<<GRID_BLOCKS, 256, 0, stream>>>(t, x, wgt, bias, out);
}